// Round 10
// baseline (195.957 us; speedup 1.0000x reference)
//
#include <hip/hip_runtime.h>
#include <hip/hip_fp16.h>

typedef int v4i __attribute__((ext_vector_type(4)));
typedef int v16i __attribute__((ext_vector_type(16)));

#define QMAXF 127.0f
#define EPSF 1e-8f

// ---------------------------------------------------------------------------
// Per-row symmetric int8 quantization (validated round 1).
// ---------------------------------------------------------------------------
template <bool WEIGHT>
__global__ __launch_bounds__(256) void quant_rows(
    const float* __restrict__ src, signed char* __restrict__ q,
    float* __restrict__ scale, int ncols) {
  const int row = blockIdx.x;
  const int t = threadIdx.x;
  const float4* s4 = (const float4*)(src + (size_t)row * ncols);

  float4 v[4];
  float am = 0.f;
#pragma unroll
  for (int p = 0; p < 4; ++p) {
    v[p] = s4[p * 256 + t];
    am = fmaxf(am, fmaxf(fmaxf(fabsf(v[p].x), fabsf(v[p].y)),
                         fmaxf(fabsf(v[p].z), fabsf(v[p].w))));
  }
#pragma unroll
  for (int off = 32; off > 0; off >>= 1) am = fmaxf(am, __shfl_xor(am, off));
  __shared__ float red[4];
  if ((t & 63) == 0) red[t >> 6] = am;
  __syncthreads();
  am = fmaxf(fmaxf(red[0], red[1]), fmaxf(red[2], red[3]));

  const float s = fmaxf(am, EPSF) / QMAXF;

  uint32_t* qrow = (uint32_t*)(q + (size_t)row * ncols);
#pragma unroll
  for (int p = 0; p < 4; ++p) {
    float fx = fminf(fmaxf(rintf(v[p].x / s), -QMAXF), QMAXF);
    float fy = fminf(fmaxf(rintf(v[p].y / s), -QMAXF), QMAXF);
    float fz = fminf(fmaxf(rintf(v[p].z / s), -QMAXF), QMAXF);
    float fw = fminf(fmaxf(rintf(v[p].w / s), -QMAXF), QMAXF);
    qrow[p * 256 + t] = ((uint32_t)((int)fx & 0xff)) |
                        ((uint32_t)((int)fy & 0xff) << 8) |
                        ((uint32_t)((int)fz & 0xff) << 16) |
                        ((uint32_t)((int)fw & 0xff) << 24);
  }
  if (t == 0) {
    float so = s;
    if (WEIGHT) so = __half2float(__float2half(s));
    scale[row] = so;
  }
}

// ---------------------------------------------------------------------------
// 256x256 8-wave int8 GEMM — round-10: validated round-6 structure
// (staging, buffers, barriers, counted-vmcnt ledger all byte-identical),
// MFMA shape switched 16x16x64 -> 32x32x32 (+11% matrix throughput, half
// the MFMA instruction count, identical fragment bytes / LDS traffic).
//   A-frag (m-tile mt): row = wm*128 + mt*32 + (lane&31),
//                       kbytes = s*32 + (lane>>5)*16   (s = kstep 0..3)
//   B-frag (n-tile nt): row = wn*64 + nt*32 + (lane&31), same kbytes
//   C/D: col = lane&31, row = (reg&3) + 8*(reg>>2) + 4*(lane>>5)
// Lesson from r8/r9 (2 failures): counted-vmcnt ledgers are only sound on a
// HOMOGENEOUS global_load_lds queue; mixing plain global_loads into the
// queue gives schedule/retire-order-dependent races. All VMEM here is
// gload_lds again.
// ---------------------------------------------------------------------------
__device__ __forceinline__ void gload16(const void* g, void* l) {
  __builtin_amdgcn_global_load_lds(
      (const __attribute__((address_space(1))) void*)g,
      (__attribute__((address_space(3))) void*)l, 16, 0, 0);
}

#define STAGE_A(dst, br0, ktoff)                                            \
  do {                                                                      \
    gload16(Ap + (size_t)((br0) + lr) * K + (ktoff) + scsw,                 \
            (dst) + ((br0) + lr) * 128 + sc);                               \
    gload16(Ap + (size_t)((br0) + 128 + lr) * K + (ktoff) + scsw,           \
            (dst) + ((br0) + 128 + lr) * 128 + sc);                         \
  } while (0)

#define STAGE_B(dst, nh, ktoff)                                             \
  do {                                                                      \
    const int r_ = (nh)*32 + lr + (lr & 32);                                \
    gload16(Bp + (size_t)(r_) * K + (ktoff) + scsw, (dst) + r_ * 128 + sc); \
    gload16(Bp + (size_t)(r_ + 128) * K + (ktoff) + scsw,                   \
            (dst) + (r_ + 128) * 128 + sc);                                 \
  } while (0)

// A-fragments for half MH (m-tiles MH*2, MH*2+1), all 4 ksteps: 8 reads
#define READ_A32(MH)                                                        \
  _Pragma("unroll") for (int mi = 0; mi < 2; ++mi)                          \
      _Pragma("unroll") for (int s = 0; s < 4; ++s)                         \
          af[mi][s] = *(const v4i*)(Ad + (a32 + ((MH)*2 + mi) * 32) * 128 + \
                                    ((s * 32 + ac16) ^ ax))

// B-fragments for both n-tiles, all 4 ksteps: 8 reads
#define READ_B32()                                                          \
  _Pragma("unroll") for (int ni = 0; ni < 2; ++ni)                          \
      _Pragma("unroll") for (int s = 0; s < 4; ++s)                         \
          bf[ni][s] = *(const v4i*)(Bd + (b32 + ni * 32) * 128 +            \
                                    ((s * 32 + ac16) ^ ax))

// 16 MFMAs: m-tiles MB0..MB0+1 x n-tiles 0..1 x ksteps 0..3
#define MFMA_HALF(MB0)                                                      \
  _Pragma("unroll") for (int s = 0; s < 4; ++s)                             \
      _Pragma("unroll") for (int mi = 0; mi < 2; ++mi)                      \
          _Pragma("unroll") for (int ni = 0; ni < 2; ++ni)                  \
              acc[(MB0) + mi][ni] = __builtin_amdgcn_mfma_i32_32x32x32_i8(  \
                  af[mi][s], bf[ni][s], acc[(MB0) + mi][ni], 0, 0, 0)

__global__ __launch_bounds__(512, 2) void gemm_i8(
    const signed char* __restrict__ A,  // xq [M][K]
    const signed char* __restrict__ B,  // wq [N][K]
    const float* __restrict__ xsc,      // [M]
    const float* __restrict__ wsc,      // [N]
    const float* __restrict__ bias,     // [N]
    float* __restrict__ out, int M, int N, int K) {
  __shared__ __align__(16) signed char lds[131072];
  signed char* const ldsA = lds;          // [2][256][128]
  signed char* const ldsB = lds + 65536;  // [2][256][128]

  const int tid = threadIdx.x;
  const int lane = tid & 63;
  const int wid = tid >> 6;  // 0..7
  const int wm = wid >> 2;   // 0..1
  const int wn = wid & 3;    // 0..3
  const int bm0 = blockIdx.x * 256;
  const int bn0 = blockIdx.y * 256;

  const signed char* Ap = A + (size_t)bm0 * K;
  const signed char* Bp = B + (size_t)bn0 * K;

  // staging geometry (per thread): one 16B chunk of a 64-row x 128B block
  const int lr = tid >> 3;                // 0..63 row within 8KB block
  const int sc = (tid & 7) << 4;          // linear dest col byte
  const int scsw = sc ^ ((lr & 7) << 4);  // pre-swizzled SOURCE col

  // 32x32 read geometry (per lane)
  const int a32 = wm * 128 + (lane & 31);
  const int b32 = wn * 64 + (lane & 31);
  const int ac16 = (lane >> 5) << 4;  // 16B half of the 32B kstep
  const int ax = (lane & 7) << 4;     // XOR deswizzle (row&7 == lane&7)

  v16i acc[4][2];
#pragma unroll
  for (int i = 0; i < 4; ++i)
#pragma unroll
    for (int j = 0; j < 2; ++j) acc[i][j] = (v16i)(0);

  const int NKT = K >> 7;  // 32 K-tiles of 128 bytes

  // ---- prologue: kt0 fully + {SA0,SB0}(kt1); drain to 4 outstanding ----
  STAGE_A(ldsA, 0, 0);            // SA0(0)
  STAGE_B(ldsB, 0, 0);            // SB0(0)
  STAGE_A(ldsA, 64, 0);           // SA1(0)
  STAGE_B(ldsB, 1, 0);            // SB1(0)
  STAGE_A(ldsA + 32768, 0, 128);  // SA0(1)
  STAGE_B(ldsB + 32768, 0, 128);  // SB0(1)
  asm volatile("s_waitcnt vmcnt(4)" ::: "memory");
  __builtin_amdgcn_sched_barrier(0);
  __builtin_amdgcn_s_barrier();

  for (int kt = 0; kt < NKT; ++kt) {
    const int d = kt & 1;
    const signed char* Ad = ldsA + d * 32768;
    const signed char* Bd = ldsB + d * 32768;
    signed char* const An = ldsA + (d ^ 1) * 32768;
    signed char* const Bn = ldsB + (d ^ 1) * 32768;
    const int ko1 = (kt + 1) << 7;
    const int ko2 = (kt + 2) << 7;

    v4i af[2][4];  // A m-tile pair fragments (per window)
    v4i bf[2][4];  // B n-tile fragments (read w1, used w1+w2)

    // ---- window 1: reads(16) -> stages(SA1,SB1 of kt+1) -> 16 MFMA ----
    READ_A32(0);
    READ_B32();
    if (kt + 1 < NKT) {
      STAGE_A(An, 64, ko1);
      STAGE_B(Bn, 1, ko1);
    }
    __builtin_amdgcn_s_setprio(1);
    MFMA_HALF(0);
    __builtin_amdgcn_s_setprio(0);
    __builtin_amdgcn_s_barrier();

    // ---- window 2: reads(8) -> stages(SA0,SB0 of kt+2) -> 16 MFMA ----
    READ_A32(1);
    if (kt + 2 < NKT) {
      STAGE_A((signed char*)Ad, 0, ko2);
      STAGE_B((signed char*)Bd, 0, ko2);
    }
    __builtin_amdgcn_s_setprio(1);
    MFMA_HALF(2);
    __builtin_amdgcn_s_setprio(0);
    // counted drain in steady state; full drain once staging stops
    if (kt < NKT - 2) {
      asm volatile("s_waitcnt vmcnt(4)" ::: "memory");
    } else {
      asm volatile("s_waitcnt vmcnt(0)" ::: "memory");
    }
    __builtin_amdgcn_sched_barrier(0);
    __builtin_amdgcn_s_barrier();
  }

  // ---- epilogue: dequant + fp16-roundtripped bias, fp32 store ----
  // C/D 32x32 layout: col = lane&31, row = (reg&3) + 8*(reg>>2) + 4*(lane>>5)
#pragma unroll
  for (int mt = 0; mt < 4; ++mt) {
    const int rbase = bm0 + wm * 128 + mt * 32 + ((lane >> 5) << 2);
#pragma unroll
    for (int nt = 0; nt < 2; ++nt) {
      const int n = bn0 + wn * 64 + nt * 32 + (lane & 31);
      const float wsn = wsc[n];
      const float bn_ = __half2float(__float2half(bias[n]));
#pragma unroll
      for (int g = 0; g < 4; ++g) {
        const int m0 = rbase + 8 * g;
        const float4 xs = *(const float4*)&xsc[m0];
        const float xsv[4] = {xs.x, xs.y, xs.z, xs.w};
#pragma unroll
        for (int j = 0; j < 4; ++j) {
          out[(size_t)(m0 + j) * N + n] =
              (float)acc[mt][nt][g * 4 + j] * xsv[j] * wsn + bn_;
        }
      }
    }
  }
}

extern "C" void kernel_launch(void* const* d_in, const int* in_sizes, int n_in,
                              void* d_out, int out_size, void* d_ws,
                              size_t ws_size, hipStream_t stream) {
  const float* x = (const float*)d_in[0];     // [M][K] fp32
  const float* w = (const float*)d_in[1];     // [N][K] fp32
  const float* bias = (const float*)d_in[2];  // [N] fp32
  float* out = (float*)d_out;

  const int K = 4096;
  const int Nw = in_sizes[1] / K;  // 4096
  const int M = in_sizes[0] / K;   // 8192

  signed char* wq = (signed char*)d_ws;
  signed char* xq = wq + (size_t)Nw * K;
  float* wsc = (float*)(xq + (size_t)M * K);
  float* xsc = wsc + Nw;

  quant_rows<true><<<Nw, 256, 0, stream>>>(w, wq, wsc, K);
  quant_rows<false><<<M, 256, 0, stream>>>(x, xq, xsc, K);

  dim3 g2(M / 256, Nw / 256, 1);
  gemm_i8<<<g2, 512, 0, stream>>>(xq, wq, xsc, wsc, bias, out, M, Nw, K);
}

// Round 11
// 190.873 us; speedup vs baseline: 1.0266x; 1.0266x over previous
//
#include <hip/hip_runtime.h>
#include <hip/hip_fp16.h>

typedef int v4i __attribute__((ext_vector_type(4)));

#define QMAXF 127.0f
#define EPSF 1e-8f

// ---------------------------------------------------------------------------
// Per-row symmetric int8 quantization (validated round 1).
// ---------------------------------------------------------------------------
template <bool WEIGHT>
__global__ __launch_bounds__(256) void quant_rows(
    const float* __restrict__ src, signed char* __restrict__ q,
    float* __restrict__ scale, int ncols) {
  const int row = blockIdx.x;
  const int t = threadIdx.x;
  const float4* s4 = (const float4*)(src + (size_t)row * ncols);

  float4 v[4];
  float am = 0.f;
#pragma unroll
  for (int p = 0; p < 4; ++p) {
    v[p] = s4[p * 256 + t];
    am = fmaxf(am, fmaxf(fmaxf(fabsf(v[p].x), fabsf(v[p].y)),
                         fmaxf(fabsf(v[p].z), fabsf(v[p].w))));
  }
#pragma unroll
  for (int off = 32; off > 0; off >>= 1) am = fmaxf(am, __shfl_xor(am, off));
  __shared__ float red[4];
  if ((t & 63) == 0) red[t >> 6] = am;
  __syncthreads();
  am = fmaxf(fmaxf(red[0], red[1]), fmaxf(red[2], red[3]));

  const float s = fmaxf(am, EPSF) / QMAXF;

  uint32_t* qrow = (uint32_t*)(q + (size_t)row * ncols);
#pragma unroll
  for (int p = 0; p < 4; ++p) {
    float fx = fminf(fmaxf(rintf(v[p].x / s), -QMAXF), QMAXF);
    float fy = fminf(fmaxf(rintf(v[p].y / s), -QMAXF), QMAXF);
    float fz = fminf(fmaxf(rintf(v[p].z / s), -QMAXF), QMAXF);
    float fw = fminf(fmaxf(rintf(v[p].w / s), -QMAXF), QMAXF);
    qrow[p * 256 + t] = ((uint32_t)((int)fx & 0xff)) |
                        ((uint32_t)((int)fy & 0xff) << 8) |
                        ((uint32_t)((int)fz & 0xff) << 16) |
                        ((uint32_t)((int)fw & 0xff) << 24);
  }
  if (t == 0) {
    float so = s;
    if (WEIGHT) so = __half2float(__float2half(s));
    scale[row] = so;
  }
}

// ---------------------------------------------------------------------------
// 256x256 8-wave int8 GEMM — round-11: 4-region BK=64 rotation with
// cross-step REGISTER prefetch (removes the per-window ds_read latency
// stall that r5-r7 scheduling variants could not).
//   64 K-steps of 64 B. LDS = 4 regions x 32 KB ([256 A rows][64] +
//   [256 B rows][64], row stride 64 B, XOR swizzle (row&3)<<4 both sides).
//   Step s: STAGE(s+3) -> vmcnt(8)+lgkm(0) -> barrier -> FRAG(s+1) || MFMA(s).
//   MFMA consumes registers read LAST step => no in-step LDS stall; the 12
//   ds_reads of FRAG(s+1) land under the 32 MFMAs.
//   Ledger (4 loads/thread/stage, homogeneous gload_lds queue — r8/r9
//   lesson): entering step s in-flight {stage(s+1),stage(s+2)}=8; +stage(s+3)
//   =12; vmcnt(8) drains stage(s+1) => r(s+1) published at the barrier.
//   Tail: s==61 vmcnt(4), s>=62 vmcnt(0). Region safety: stage(s+3) targets
//   r(s-1), last read by FRAG at step s-2, two barriers earlier; lgkmcnt(0)
//   before each barrier retires reads before any overwrite can land.
// ---------------------------------------------------------------------------
__device__ __forceinline__ void gload16(const void* g, void* l) {
  __builtin_amdgcn_global_load_lds(
      (const __attribute__((address_space(1))) void*)g,
      (__attribute__((address_space(3))) void*)l, 16, 0, 0);
}

// Stage K-step s into region (s&3): 4 x gload16 per thread.
// dest per (wave,j) is base + lane*16 (linear) = lds + r*32768 + j*8192 + tid*16.
#define STAGE(s)                                                            \
  do {                                                                      \
    signed char* const rb_ = lds + ((s)&3) * 32768;                         \
    const int ko_ = (s) << 6;                                               \
    gload16(gA0 + ko_, rb_ + dst0);                                         \
    gload16(gA1 + ko_, rb_ + 8192 + dst0);                                  \
    gload16(gB0 + ko_, rb_ + 16384 + dst0);                                 \
    gload16(gB1 + ko_, rb_ + 24576 + dst0);                                 \
  } while (0)

// Prefetch fragments of K-step s into (AF, BF): 8 + 4 ds_read_b128.
#define FRAG(AF, BF, s)                                                     \
  do {                                                                      \
    const signed char* rb_ = lds + ((s)&3) * 32768;                         \
    const signed char* pa_ = rb_ + aoff;                                    \
    const signed char* pb_ = rb_ + boff;                                    \
    _Pragma("unroll") for (int mi = 0; mi < 8; ++mi)                        \
        AF[mi] = *(const v4i*)(pa_ + mi * 1024);                            \
    _Pragma("unroll") for (int ni = 0; ni < 4; ++ni)                        \
        BF[ni] = *(const v4i*)(pb_ + ni * 1024);                            \
  } while (0)

// 32 MFMAs on the register-resident fragment set.
#define MFMA32(AF, BF)                                                      \
  _Pragma("unroll") for (int mi = 0; mi < 8; ++mi)                          \
      _Pragma("unroll") for (int ni = 0; ni < 4; ++ni)                      \
          acc[mi][ni] = __builtin_amdgcn_mfma_i32_16x16x64_i8(              \
              AF[mi], BF[ni], acc[mi][ni], 0, 0, 0)

// One step: stage+wait -> barrier -> prefetch next frags || MFMA current.
#define STEP(s, CA, CB, NA, NB)                                             \
  do {                                                                      \
    if ((s) + 3 < 64) {                                                     \
      STAGE((s) + 3);                                                       \
      asm volatile("s_waitcnt vmcnt(8) lgkmcnt(0)" ::: "memory");           \
    } else if ((s) == 61) {                                                 \
      asm volatile("s_waitcnt vmcnt(4) lgkmcnt(0)" ::: "memory");           \
    } else {                                                                \
      asm volatile("s_waitcnt vmcnt(0) lgkmcnt(0)" ::: "memory");           \
    }                                                                       \
    __builtin_amdgcn_sched_barrier(0);                                      \
    __builtin_amdgcn_s_barrier();                                           \
    __builtin_amdgcn_sched_barrier(0);                                      \
    if ((s) + 1 < 64) FRAG(NA, NB, (s) + 1);                                \
    __builtin_amdgcn_s_setprio(1);                                          \
    MFMA32(CA, CB);                                                         \
    __builtin_amdgcn_s_setprio(0);                                          \
  } while (0)

__global__ __launch_bounds__(512, 2) void gemm_i8(
    const signed char* __restrict__ A,  // xq [M][K]
    const signed char* __restrict__ B,  // wq [N][K]
    const float* __restrict__ xsc,      // [M]
    const float* __restrict__ wsc,      // [N]
    const float* __restrict__ bias,     // [N]
    float* __restrict__ out, int M, int N, int K) {
  __shared__ __align__(16) signed char lds[131072];  // 4 regions x 32 KB

  const int tid = threadIdx.x;
  const int lane = tid & 63;
  const int wid = tid >> 6;  // 0..7
  const int wm = wid >> 2;   // 0..1
  const int wn = wid & 3;    // 0..3
  const int bm0 = blockIdx.x * 256;
  const int bn0 = blockIdx.y * 256;

  // ---- staging geometry: thread t covers row srow(+128) chunk sch ----
  const int srow = tid >> 2;  // 0..127
  const int sch = tid & 3;    // 16B chunk within 64B step-slab
  const int scsw = (sch << 4) ^ ((srow & 3) << 4);  // pre-swizzled src col
  const signed char* gA0 = A + (size_t)(bm0 + srow) * K + scsw;
  const signed char* gA1 = gA0 + (size_t)128 * K;
  const signed char* gB0 = B + (size_t)(bn0 + srow) * K + scsw;
  const signed char* gB1 = gB0 + (size_t)128 * K;
  const int dst0 = tid << 4;  // lane-linear LDS dest (j adds 8192)

  // ---- fragment read geometry ----
  const int fcol = (((lane >> 4) << 4) ^ ((lane & 3) << 4));
  const int aoff = (wm * 128 + (lane & 15)) * 64 + fcol;
  const int boff = 16384 + (wn * 64 + (lane & 15)) * 64 + fcol;

  v4i acc[8][4];
#pragma unroll
  for (int i = 0; i < 8; ++i)
#pragma unroll
    for (int j = 0; j < 4; ++j) acc[i][j] = (v4i){0, 0, 0, 0};

  v4i afA[8], bfA[4], afB[8], bfB[4];

  // ---- prologue: stage steps 0,1,2; publish r0; prefetch frags[0] ----
  STAGE(0);
  STAGE(1);
  STAGE(2);
  asm volatile("s_waitcnt vmcnt(8) lgkmcnt(0)" ::: "memory");
  __builtin_amdgcn_sched_barrier(0);
  __builtin_amdgcn_s_barrier();
  __builtin_amdgcn_sched_barrier(0);
  FRAG(afA, bfA, 0);

  // ---- 64 steps, unrolled x2 for static cur/nxt frag sets ----
  for (int s2 = 0; s2 < 64; s2 += 2) {
    STEP(s2, afA, bfA, afB, bfB);
    STEP(s2 + 1, afB, bfB, afA, bfA);
  }

  // ---- epilogue: dequant + fp16-roundtripped bias, fp32 store ----
#pragma unroll
  for (int mi = 0; mi < 8; ++mi) {
    const int m0 = bm0 + wm * 128 + mi * 16 + ((lane >> 4) << 2);
    const float4 xs = *(const float4*)&xsc[m0];
    const float xsv[4] = {xs.x, xs.y, xs.z, xs.w};
#pragma unroll
    for (int ni = 0; ni < 4; ++ni) {
      const int n = bn0 + wn * 64 + ni * 16 + (lane & 15);
      const float wsn = wsc[n];
      const float bn_ = __half2float(__float2half(bias[n]));
#pragma unroll
      for (int r = 0; r < 4; ++r) {
        out[(size_t)(m0 + r) * N + n] =
            (float)acc[mi][ni][r] * xsv[r] * wsn + bn_;
      }
    }
  }
}

extern "C" void kernel_launch(void* const* d_in, const int* in_sizes, int n_in,
                              void* d_out, int out_size, void* d_ws,
                              size_t ws_size, hipStream_t stream) {
  const float* x = (const float*)d_in[0];     // [M][K] fp32
  const float* w = (const float*)d_in[1];     // [N][K] fp32
  const float* bias = (const float*)d_in[2];  // [N] fp32
  float* out = (float*)d_out;

  const int K = 4096;
  const int Nw = in_sizes[1] / K;  // 4096
  const int M = in_sizes[0] / K;   // 8192

  signed char* wq = (signed char*)d_ws;
  signed char* xq = wq + (size_t)Nw * K;
  float* wsc = (float*)(xq + (size_t)M * K);
  float* xsc = wsc + Nw;

  quant_rows<true><<<Nw, 256, 0, stream>>>(w, wq, wsc, K);
  quant_rows<false><<<M, 256, 0, stream>>>(x, xq, xsc, K);

  dim3 g2(M / 256, Nw / 256, 1);
  gemm_i8<<<g2, 512, 0, stream>>>(xq, wq, xsc, wsc, bias, out, M, Nw, K);
}

// Round 12
// 184.813 us; speedup vs baseline: 1.0603x; 1.0328x over previous
//
#include <hip/hip_runtime.h>
#include <hip/hip_fp16.h>

typedef int v4i __attribute__((ext_vector_type(4)));

#define QMAXF 127.0f
#define EPSF 1e-8f

// ---------------------------------------------------------------------------
// Per-row symmetric int8 quantization (validated round 1).
// ---------------------------------------------------------------------------
template <bool WEIGHT>
__global__ __launch_bounds__(256) void quant_rows(
    const float* __restrict__ src, signed char* __restrict__ q,
    float* __restrict__ scale, int ncols) {
  const int row = blockIdx.x;
  const int t = threadIdx.x;
  const float4* s4 = (const float4*)(src + (size_t)row * ncols);

  float4 v[4];
  float am = 0.f;
#pragma unroll
  for (int p = 0; p < 4; ++p) {
    v[p] = s4[p * 256 + t];
    am = fmaxf(am, fmaxf(fmaxf(fabsf(v[p].x), fabsf(v[p].y)),
                         fmaxf(fabsf(v[p].z), fabsf(v[p].w))));
  }
#pragma unroll
  for (int off = 32; off > 0; off >>= 1) am = fmaxf(am, __shfl_xor(am, off));
  __shared__ float red[4];
  if ((t & 63) == 0) red[t >> 6] = am;
  __syncthreads();
  am = fmaxf(fmaxf(red[0], red[1]), fmaxf(red[2], red[3]));

  const float s = fmaxf(am, EPSF) / QMAXF;

  uint32_t* qrow = (uint32_t*)(q + (size_t)row * ncols);
#pragma unroll
  for (int p = 0; p < 4; ++p) {
    float fx = fminf(fmaxf(rintf(v[p].x / s), -QMAXF), QMAXF);
    float fy = fminf(fmaxf(rintf(v[p].y / s), -QMAXF), QMAXF);
    float fz = fminf(fmaxf(rintf(v[p].z / s), -QMAXF), QMAXF);
    float fw = fminf(fmaxf(rintf(v[p].w / s), -QMAXF), QMAXF);
    qrow[p * 256 + t] = ((uint32_t)((int)fx & 0xff)) |
                        ((uint32_t)((int)fy & 0xff) << 8) |
                        ((uint32_t)((int)fz & 0xff) << 16) |
                        ((uint32_t)((int)fw & 0xff) << 24);
  }
  if (t == 0) {
    float so = s;
    if (WEIGHT) so = __half2float(__float2half(s));
    scale[row] = so;
  }
}

// ---------------------------------------------------------------------------
// 256x256 8-wave int8 GEMM — round-12: r6's validated components (layouts,
// (row&7)<<4 swizzle, staging macros, epilogue) with the K-loop stripped to
// the minimum 2-phase: ONE window + ONE barrier per 128-B K-tile.
//   iter kt: STAGE full tile kt+1 (8 gloads) -> 24 consumption-ordered
//   ds_reads -> 64 MFMAs -> vmcnt(0) -> barrier.
// Hazards: stage targets buf d^1, last read one barrier earlier; all
// ds_reads consumed in-window (drained before barrier by data dep);
// vmcnt(0) issue->drain distance = full iteration (~2600 cyc >> 900-cyc
// HBM latency) so the drain is cheap. Barriers 64 -> 32 total.
// r8/r9 lesson kept: homogeneous gload_lds VMEM queue only.
// ---------------------------------------------------------------------------
__device__ __forceinline__ void gload16(const void* g, void* l) {
  __builtin_amdgcn_global_load_lds(
      (const __attribute__((address_space(1))) void*)g,
      (__attribute__((address_space(3))) void*)l, 16, 0, 0);
}

#define STAGE_A(dst, br0, ktoff)                                            \
  do {                                                                      \
    gload16(Ap + (size_t)((br0) + lr) * K + (ktoff) + scsw,                 \
            (dst) + ((br0) + lr) * 128 + sc);                               \
    gload16(Ap + (size_t)((br0) + 128 + lr) * K + (ktoff) + scsw,           \
            (dst) + ((br0) + 128 + lr) * 128 + sc);                         \
  } while (0)

#define STAGE_B(dst, nh, ktoff)                                             \
  do {                                                                      \
    const int r_ = (nh)*32 + lr + (lr & 32);                                \
    gload16(Bp + (size_t)(r_) * K + (ktoff) + scsw, (dst) + r_ * 128 + sc); \
    gload16(Bp + (size_t)(r_ + 128) * K + (ktoff) + scsw,                   \
            (dst) + (r_ + 128) * 128 + sc);                                 \
  } while (0)

// A-fragments (8 x ds_read_b128) for k-substep ks
#define READ_AF64(ks)                                                       \
  _Pragma("unroll") for (int mi = 0; mi < 8; ++mi)                          \
      af[mi] = *(const v4i*)(Ad + (arow + mi * 16) * 128 +                  \
                             ((ac0 + (ks)*64) ^ axor))

// B-fragments (4 x ds_read_b128) for k-substep ks into dst
#define READ_BF64(dst, ks)                                                  \
  _Pragma("unroll") for (int ni = 0; ni < 4; ++ni)                          \
      dst[ni] = *(const v4i*)(Bd + (brow + ni * 16) * 128 +                 \
                              ((ac0 + (ks)*64) ^ bxor))

// 32 MFMAs: full 128x64 wave tile for one k-substep (mi-major so af[mi]
// frees early, letting the next substep's af reads issue in cascade).
#define MFMA_SET(AF, BF)                                                    \
  _Pragma("unroll") for (int mi = 0; mi < 8; ++mi)                          \
      _Pragma("unroll") for (int ni = 0; ni < 4; ++ni)                      \
          acc[mi][ni] = __builtin_amdgcn_mfma_i32_16x16x64_i8(              \
              AF[mi], BF[ni], acc[mi][ni], 0, 0, 0)

__global__ __launch_bounds__(512, 2) void gemm_i8(
    const signed char* __restrict__ A,  // xq [M][K]
    const signed char* __restrict__ B,  // wq [N][K]
    const float* __restrict__ xsc,      // [M]
    const float* __restrict__ wsc,      // [N]
    const float* __restrict__ bias,     // [N]
    float* __restrict__ out, int M, int N, int K) {
  __shared__ __align__(16) signed char lds[131072];
  signed char* const ldsA = lds;          // [2][256][128]
  signed char* const ldsB = lds + 65536;  // [2][256][128]

  const int tid = threadIdx.x;
  const int lane = tid & 63;
  const int wid = tid >> 6;  // 0..7
  const int wm = wid >> 2;   // 0..1
  const int wn = wid & 3;    // 0..3
  const int bm0 = blockIdx.x * 256;
  const int bn0 = blockIdx.y * 256;

  const signed char* Ap = A + (size_t)bm0 * K;
  const signed char* Bp = B + (size_t)bn0 * K;

  // staging geometry (per thread): one 16B chunk of a 64-row x 128B block
  const int lr = tid >> 3;                // 0..63 row within 8KB block
  const int sc = (tid & 7) << 4;          // linear dest col byte
  const int scsw = sc ^ ((lr & 7) << 4);  // pre-swizzled SOURCE col

  // read geometry (per lane) — r6-validated conflict-free
  const int arow = wm * 128 + (lane & 15);
  const int brow = wn * 64 + (lane & 15);
  const int ac0 = (lane >> 4) << 4;  // 16B k-chunk within 64B ksub
  const int axor = (arow & 7) << 4;
  const int bxor = (brow & 7) << 4;

  v4i acc[8][4];
#pragma unroll
  for (int i = 0; i < 8; ++i)
#pragma unroll
    for (int j = 0; j < 4; ++j) acc[i][j] = (v4i){0, 0, 0, 0};

  const int NKT = K >> 7;  // 32 K-tiles of 128 bytes

  // ---- prologue: stage tile 0 into buf0; publish ----
  STAGE_A(ldsA, 0, 0);
  STAGE_A(ldsA, 64, 0);
  STAGE_B(ldsB, 0, 0);
  STAGE_B(ldsB, 1, 0);
  asm volatile("s_waitcnt vmcnt(0)" ::: "memory");
  __builtin_amdgcn_sched_barrier(0);
  __builtin_amdgcn_s_barrier();

  for (int kt = 0; kt < NKT; ++kt) {
    const int d = kt & 1;
    const signed char* Ad = ldsA + d * 32768;
    const signed char* Bd = ldsB + d * 32768;
    signed char* const An = ldsA + (d ^ 1) * 32768;
    signed char* const Bn = ldsB + (d ^ 1) * 32768;
    const int ko1 = (kt + 1) << 7;

    v4i af[8];   // A frags (renamed across ks0/ks1 by SSA)
    v4i bf[4];   // B ks0
    v4i bf2[4];  // B ks1 (separate regs: reads issue at window top)

    // ---- stage next tile (8 gloads, drained at window end) ----
    if (kt + 1 < NKT) {
      STAGE_A(An, 0, ko1);
      STAGE_A(An, 64, ko1);
      STAGE_B(Bn, 0, ko1);
      STAGE_B(Bn, 1, ko1);
    }
    // ---- consumption-ordered reads; compiler gates with counted lgkm ----
    READ_BF64(bf, 0);
    READ_AF64(0);
    READ_BF64(bf2, 1);
    __builtin_amdgcn_s_setprio(1);
    MFMA_SET(af, bf);  // ks0: 32 MFMAs
    __builtin_amdgcn_s_setprio(0);
    READ_AF64(1);  // af ks1 — WAR cascade behind ks0 consumption
    __builtin_amdgcn_s_setprio(1);
    MFMA_SET(af, bf2);  // ks1: 32 MFMAs
    __builtin_amdgcn_s_setprio(0);
    // ---- publish staged tile; single barrier per K-tile ----
    asm volatile("s_waitcnt vmcnt(0)" ::: "memory");
    __builtin_amdgcn_sched_barrier(0);
    __builtin_amdgcn_s_barrier();
  }

  // ---- epilogue: dequant + fp16-roundtripped bias, fp32 store ----
#pragma unroll
  for (int mi = 0; mi < 8; ++mi) {
    const int m0 = bm0 + wm * 128 + mi * 16 + ((lane >> 4) << 2);
    const float4 xs = *(const float4*)&xsc[m0];
    const float xsv[4] = {xs.x, xs.y, xs.z, xs.w};
#pragma unroll
    for (int ni = 0; ni < 4; ++ni) {
      const int n = bn0 + wn * 64 + ni * 16 + (lane & 15);
      const float wsn = wsc[n];
      const float bn_ = __half2float(__float2half(bias[n]));
#pragma unroll
      for (int r = 0; r < 4; ++r) {
        out[(size_t)(m0 + r) * N + n] =
            (float)acc[mi][ni][r] * xsv[r] * wsn + bn_;
      }
    }
  }
}

extern "C" void kernel_launch(void* const* d_in, const int* in_sizes, int n_in,
                              void* d_out, int out_size, void* d_ws,
                              size_t ws_size, hipStream_t stream) {
  const float* x = (const float*)d_in[0];     // [M][K] fp32
  const float* w = (const float*)d_in[1];     // [N][K] fp32
  const float* bias = (const float*)d_in[2];  // [N] fp32
  float* out = (float*)d_out;

  const int K = 4096;
  const int Nw = in_sizes[1] / K;  // 4096
  const int M = in_sizes[0] / K;   // 8192

  signed char* wq = (signed char*)d_ws;
  signed char* xq = wq + (size_t)Nw * K;
  float* wsc = (float*)(xq + (size_t)M * K);
  float* xsc = wsc + Nw;

  quant_rows<true><<<Nw, 256, 0, stream>>>(w, wq, wsc, K);
  quant_rows<false><<<M, 256, 0, stream>>>(x, xq, xsc, K);

  dim3 g2(M / 256, Nw / 256, 1);
  gemm_i8<<<g2, 512, 0, stream>>>(xq, wq, xsc, wsc, bias, out, M, Nw, K);
}

// Round 13
// 184.723 us; speedup vs baseline: 1.0608x; 1.0005x over previous
//
#include <hip/hip_runtime.h>
#include <hip/hip_fp16.h>

typedef int v4i __attribute__((ext_vector_type(4)));

#define QMAXF 127.0f
#define EPSF 1e-8f

// ---------------------------------------------------------------------------
// Fused per-row quantization: blocks [0,Nw) quantize weight rows (fp16-
// roundtripped scale), blocks [Nw, Nw+M) quantize activation rows.
// Same validated round-1 body; one dispatch instead of two.
// ---------------------------------------------------------------------------
__global__ __launch_bounds__(256) void quant_all(
    const float* __restrict__ w, const float* __restrict__ x,
    signed char* __restrict__ wq, signed char* __restrict__ xq,
    float* __restrict__ wsc, float* __restrict__ xsc, int Nw, int ncols) {
  const int b = blockIdx.x;
  const bool is_w = b < Nw;
  const int row = is_w ? b : b - Nw;
  const float* __restrict__ src = is_w ? w : x;
  signed char* __restrict__ q = is_w ? wq : xq;
  float* __restrict__ scale = is_w ? wsc : xsc;

  const int t = threadIdx.x;
  const float4* s4 = (const float4*)(src + (size_t)row * ncols);

  float4 v[4];
  float am = 0.f;
#pragma unroll
  for (int p = 0; p < 4; ++p) {
    v[p] = s4[p * 256 + t];
    am = fmaxf(am, fmaxf(fmaxf(fabsf(v[p].x), fabsf(v[p].y)),
                         fmaxf(fabsf(v[p].z), fabsf(v[p].w))));
  }
#pragma unroll
  for (int off = 32; off > 0; off >>= 1) am = fmaxf(am, __shfl_xor(am, off));
  __shared__ float red[4];
  if ((t & 63) == 0) red[t >> 6] = am;
  __syncthreads();
  am = fmaxf(fmaxf(red[0], red[1]), fmaxf(red[2], red[3]));

  const float s = fmaxf(am, EPSF) / QMAXF;

  uint32_t* qrow = (uint32_t*)(q + (size_t)row * ncols);
#pragma unroll
  for (int p = 0; p < 4; ++p) {
    float fx = fminf(fmaxf(rintf(v[p].x / s), -QMAXF), QMAXF);
    float fy = fminf(fmaxf(rintf(v[p].y / s), -QMAXF), QMAXF);
    float fz = fminf(fmaxf(rintf(v[p].z / s), -QMAXF), QMAXF);
    float fw = fminf(fmaxf(rintf(v[p].w / s), -QMAXF), QMAXF);
    qrow[p * 256 + t] = ((uint32_t)((int)fx & 0xff)) |
                        ((uint32_t)((int)fy & 0xff) << 8) |
                        ((uint32_t)((int)fz & 0xff) << 16) |
                        ((uint32_t)((int)fw & 0xff) << 24);
  }
  if (t == 0) scale[row] = is_w ? __half2float(__float2half(s)) : s;
}

// ---------------------------------------------------------------------------
// 256x256 8-wave int8 GEMM — round-13: r11's 4-region BK=64 rotation with
// cross-step register prefetch, with the CORRECT 64-B-row bank swizzle.
//   Bank of (row,chunk) = (16*row + 4*chunk) % 32: row bit 0 is consumed by
//   the 16*(row&1) term, so the spread XOR must use (row>>1)&3 (r11 used
//   row&3 -> rows 0,4,8,12 collided 4-way; 1.26e7 conflict cycles).
//   With the fix every 16-lane b128 read is 2 lanes/bank = free (m136).
//   Structure (validated r11, passed): 64 K-steps of 64 B, LDS 4 x 32 KB.
//   Step s: STAGE(s+3) -> vmcnt(8)+lgkm(0) -> barrier -> FRAG(s+1)||MFMA(s).
//   Ledger: entering s in-flight {s+1,s+2}=8; +STAGE(s+3)=12; vmcnt(8)
//   drains stage(s+1). Tail: s==61 vmcnt(4), s>=62 vmcnt(0). Homogeneous
//   gload_lds queue only (r8/r9 lesson).
// ---------------------------------------------------------------------------
__device__ __forceinline__ void gload16(const void* g, void* l) {
  __builtin_amdgcn_global_load_lds(
      (const __attribute__((address_space(1))) void*)g,
      (__attribute__((address_space(3))) void*)l, 16, 0, 0);
}

#define STAGE(s)                                                            \
  do {                                                                      \
    signed char* const rb_ = lds + ((s)&3) * 32768;                         \
    const int ko_ = (s) << 6;                                               \
    gload16(gA0 + ko_, rb_ + dst0);                                         \
    gload16(gA1 + ko_, rb_ + 8192 + dst0);                                  \
    gload16(gB0 + ko_, rb_ + 16384 + dst0);                                 \
    gload16(gB1 + ko_, rb_ + 24576 + dst0);                                 \
  } while (0)

#define FRAG(AF, BF, s)                                                     \
  do {                                                                      \
    const signed char* rb_ = lds + ((s)&3) * 32768;                         \
    const signed char* pa_ = rb_ + aoff;                                    \
    const signed char* pb_ = rb_ + boff;                                    \
    _Pragma("unroll") for (int mi = 0; mi < 8; ++mi)                        \
        AF[mi] = *(const v4i*)(pa_ + mi * 1024);                            \
    _Pragma("unroll") for (int ni = 0; ni < 4; ++ni)                        \
        BF[ni] = *(const v4i*)(pb_ + ni * 1024);                            \
  } while (0)

#define MFMA32(AF, BF)                                                      \
  _Pragma("unroll") for (int mi = 0; mi < 8; ++mi)                          \
      _Pragma("unroll") for (int ni = 0; ni < 4; ++ni)                      \
          acc[mi][ni] = __builtin_amdgcn_mfma_i32_16x16x64_i8(              \
              AF[mi], BF[ni], acc[mi][ni], 0, 0, 0)

#define STEP(s, CA, CB, NA, NB)                                             \
  do {                                                                      \
    if ((s) + 3 < 64) {                                                     \
      STAGE((s) + 3);                                                       \
      asm volatile("s_waitcnt vmcnt(8) lgkmcnt(0)" ::: "memory");           \
    } else if ((s) == 61) {                                                 \
      asm volatile("s_waitcnt vmcnt(4) lgkmcnt(0)" ::: "memory");           \
    } else {                                                                \
      asm volatile("s_waitcnt vmcnt(0) lgkmcnt(0)" ::: "memory");           \
    }                                                                       \
    __builtin_amdgcn_sched_barrier(0);                                      \
    __builtin_amdgcn_s_barrier();                                           \
    __builtin_amdgcn_sched_barrier(0);                                      \
    if ((s) + 1 < 64) FRAG(NA, NB, (s) + 1);                                \
    __builtin_amdgcn_s_setprio(1);                                          \
    MFMA32(CA, CB);                                                         \
    __builtin_amdgcn_s_setprio(0);                                          \
  } while (0)

__global__ __launch_bounds__(512, 2) void gemm_i8(
    const signed char* __restrict__ A,  // xq [M][K]
    const signed char* __restrict__ B,  // wq [N][K]
    const float* __restrict__ xsc,      // [M]
    const float* __restrict__ wsc,      // [N]
    const float* __restrict__ bias,     // [N]
    float* __restrict__ out, int M, int N, int K) {
  __shared__ __align__(16) signed char lds[131072];  // 4 regions x 32 KB

  const int tid = threadIdx.x;
  const int lane = tid & 63;
  const int wid = tid >> 6;  // 0..7
  const int wm = wid >> 2;   // 0..1
  const int wn = wid & 3;    // 0..3
  const int bm0 = blockIdx.x * 256;
  const int bn0 = blockIdx.y * 256;

  // ---- staging geometry: thread t covers rows srow/srow+128, chunk sch ----
  const int srow = tid >> 2;  // 0..127
  const int sch = tid & 3;    // 16B chunk within 64B step-slab
  // CORRECT pre-swizzle: XOR with (row>>1)&3 (invariant under row+128)
  const int scsw = (sch << 4) ^ (((srow >> 1) & 3) << 4);
  const signed char* gA0 = A + (size_t)(bm0 + srow) * K + scsw;
  const signed char* gA1 = gA0 + (size_t)128 * K;
  const signed char* gB0 = B + (size_t)(bn0 + srow) * K + scsw;
  const signed char* gB1 = gB0 + (size_t)128 * K;
  const int dst0 = tid << 4;  // lane-linear LDS dest (j adds 8192)

  // ---- fragment read geometry (frag row = lane&15; same XOR bits) ----
  const int fcol = (((lane >> 4) << 4) ^ ((((lane & 15) >> 1) & 3) << 4));
  const int aoff = (wm * 128 + (lane & 15)) * 64 + fcol;
  const int boff = 16384 + (wn * 64 + (lane & 15)) * 64 + fcol;

  v4i acc[8][4];
#pragma unroll
  for (int i = 0; i < 8; ++i)
#pragma unroll
    for (int j = 0; j < 4; ++j) acc[i][j] = (v4i){0, 0, 0, 0};

  v4i afA[8], bfA[4], afB[8], bfB[4];

  // ---- prologue: stage steps 0,1,2; publish r0; prefetch frags[0] ----
  STAGE(0);
  STAGE(1);
  STAGE(2);
  asm volatile("s_waitcnt vmcnt(8) lgkmcnt(0)" ::: "memory");
  __builtin_amdgcn_sched_barrier(0);
  __builtin_amdgcn_s_barrier();
  __builtin_amdgcn_sched_barrier(0);
  FRAG(afA, bfA, 0);

  // ---- 64 steps, unrolled x2 for static cur/nxt frag sets ----
  for (int s2 = 0; s2 < 64; s2 += 2) {
    STEP(s2, afA, bfA, afB, bfB);
    STEP(s2 + 1, afB, bfB, afA, bfA);
  }

  // ---- epilogue: dequant + fp16-roundtripped bias, fp32 store ----
#pragma unroll
  for (int mi = 0; mi < 8; ++mi) {
    const int m0 = bm0 + wm * 128 + mi * 16 + ((lane >> 4) << 2);
    const float4 xs = *(const float4*)&xsc[m0];
    const float xsv[4] = {xs.x, xs.y, xs.z, xs.w};
#pragma unroll
    for (int ni = 0; ni < 4; ++ni) {
      const int n = bn0 + wn * 64 + ni * 16 + (lane & 15);
      const float wsn = wsc[n];
      const float bn_ = __half2float(__float2half(bias[n]));
#pragma unroll
      for (int r = 0; r < 4; ++r) {
        out[(size_t)(m0 + r) * N + n] =
            (float)acc[mi][ni][r] * xsv[r] * wsn + bn_;
      }
    }
  }
}

extern "C" void kernel_launch(void* const* d_in, const int* in_sizes, int n_in,
                              void* d_out, int out_size, void* d_ws,
                              size_t ws_size, hipStream_t stream) {
  const float* x = (const float*)d_in[0];     // [M][K] fp32
  const float* w = (const float*)d_in[1];     // [N][K] fp32
  const float* bias = (const float*)d_in[2];  // [N] fp32
  float* out = (float*)d_out;

  const int K = 4096;
  const int Nw = in_sizes[1] / K;  // 4096
  const int M = in_sizes[0] / K;   // 8192

  signed char* wq = (signed char*)d_ws;
  signed char* xq = wq + (size_t)Nw * K;
  float* wsc = (float*)(xq + (size_t)M * K);
  float* xsc = wsc + Nw;

  quant_all<<<Nw + M, 256, 0, stream>>>(w, x, wq, xq, wsc, xsc, Nw, K);

  dim3 g2(M / 256, Nw / 256, 1);
  gemm_i8<<<g2, 512, 0, stream>>>(xq, wq, xsc, wsc, bias, out, M, Nw, K);
}